// Round 2
// baseline (573.398 us; speedup 1.0000x reference)
//
#include <hip/hip_runtime.h>

typedef unsigned short u16;
typedef float f32x4 __attribute__((ext_vector_type(4)));
typedef _Float16 h16x8 __attribute__((ext_vector_type(8)));

#define NB 8
#define CC 192
#define OO 96
#define NN 4096

static __device__ __forceinline__ u16 f2h(float f) {
  _Float16 h = (_Float16)f;
  return __builtin_bit_cast(u16, h);
}

// ---------------- Kernel 1: fused theta/phi/g 1x1-conv projections ----------------
// x: [B,C,N] fp32.  Outputs: QT,KT = [B,N,96] fp16 (row per n, o contiguous);
// Vn = [B,96,N] fp16 (row per o, n contiguous).
__global__ __launch_bounds__(256) void proj_kernel(
    const float* __restrict__ x,
    const float* __restrict__ g_w, const float* __restrict__ g_b,
    const float* __restrict__ th_w, const float* __restrict__ th_b,
    const float* __restrict__ ph_w, const float* __restrict__ ph_b,
    u16* __restrict__ QT, u16* __restrict__ KT, u16* __restrict__ Vn)
{
  __shared__ float xs[CC][64];
  const int b = blockIdx.y;
  const int n0 = blockIdx.x * 64;
  const int tid = threadIdx.x;
  #pragma unroll
  for (int it = 0; it < 12; ++it) {
    int idx = tid + it * 256;           // 0..3071 : 192 rows x 16 float4
    int c = idx >> 4, q = idx & 15;
    float4 v = *(const float4*)(x + ((size_t)(b * CC + c)) * NN + n0 + q * 4);
    *(float4*)&xs[c][q * 4] = v;
  }
  __syncthreads();
  const int lane = tid & 63;            // n within tile
  const int ob = (tid >> 6) * 24;       // wave-uniform o-range -> scalar w loads
  for (int p = 0; p < 3; ++p) {
    const float* w    = (p == 0) ? th_w : (p == 1) ? ph_w : g_w;
    const float* bias = (p == 0) ? th_b : (p == 1) ? ph_b : g_b;
    float acc[24];
    #pragma unroll
    for (int i = 0; i < 24; ++i) acc[i] = bias[ob + i];
    for (int c = 0; c < CC; c += 4) {
      float xv0 = xs[c + 0][lane], xv1 = xs[c + 1][lane];
      float xv2 = xs[c + 2][lane], xv3 = xs[c + 3][lane];
      #pragma unroll
      for (int i = 0; i < 24; ++i) {
        const float* wr = w + (ob + i) * CC + c;
        acc[i] += wr[0] * xv0 + wr[1] * xv1 + wr[2] * xv2 + wr[3] * xv3;
      }
    }
    if (p == 2) {  // g -> V in [B,96,N]
      #pragma unroll
      for (int i = 0; i < 24; ++i)
        Vn[((size_t)(b * OO + ob + i)) * NN + n0 + lane] = f2h(acc[i]);
    } else {       // theta -> QT, phi -> KT in [B,N,96]
      u16* dst = (p == 0 ? QT : KT) + ((size_t)(b * NN + n0 + lane)) * OO + ob;
      #pragma unroll
      for (int i = 0; i < 24; ++i) dst[i] = f2h(acc[i]);
    }
  }
}

// ---------------- Kernel 2: flash attention core (fp16 MFMA) ----------------
// Per block: batch b, 64 query rows. 4 waves x 16 rows. KV tiles of 64 staged in LDS.
__global__ __launch_bounds__(256) void attn_kernel(
    const u16* __restrict__ QT, const u16* __restrict__ KT,
    const u16* __restrict__ Vn, float* __restrict__ yT)
{
  __shared__ __align__(16) u16 Ks[64][104];     // 96 + 8 pad
  __shared__ __align__(16) u16 Vs[OO][72];      // 64 + 8 pad
  __shared__ __align__(16) u16 Ps[4][16][72];   // per-wave P tile, 64 + 8 pad
  const int b = blockIdx.y;
  const int q0 = blockIdx.x * 64;
  const int tid = threadIdx.x;
  const int lane = tid & 63;
  const int wv = tid >> 6;
  const int l15 = lane & 15;
  const int lg = lane >> 4;                     // 0..3

  // Q fragments for this wave's 16 query rows (K-dim 96 = 3 slices of 32)
  const int qrow = q0 + wv * 16 + l15;
  h16x8 qf[3];
  #pragma unroll
  for (int ks = 0; ks < 3; ++ks)
    qf[ks] = *(const h16x8*)(QT + ((size_t)(b * NN + qrow)) * OO + ks * 32 + lg * 8);

  float m_run[4], l_run[4];
  f32x4 acc[6];
  #pragma unroll
  for (int r = 0; r < 4; ++r) { m_run[r] = -__builtin_inff(); l_run[r] = 0.f; }
  #pragma unroll
  for (int o = 0; o < 6; ++o) acc[o] = (f32x4){0.f, 0.f, 0.f, 0.f};

  for (int mt = 0; mt < 64; ++mt) {
    const int m0 = mt * 64;
    __syncthreads();
    // stage K tile: 64 rows x 96 fp16
    #pragma unroll
    for (int it = 0; it < 3; ++it) {
      int idx = tid + it * 256;                 // 0..767
      int r = idx / 12, c8 = idx % 12;
      float4 v = *(const float4*)(KT + ((size_t)(b * NN + m0 + r)) * OO + c8 * 8);
      *(float4*)&Ks[r][c8 * 8] = v;
    }
    // stage V tile: 96 rows x 64 fp16
    #pragma unroll
    for (int it = 0; it < 3; ++it) {
      int idx = tid + it * 256;
      int o = idx >> 3, c8 = idx & 7;
      float4 v = *(const float4*)(Vn + ((size_t)(b * OO + o)) * NN + m0 + c8 * 8);
      *(float4*)&Vs[o][c8 * 8] = v;
    }
    __syncthreads();

    // QK^T: 4 m-subtiles x 3 k-slices
    f32x4 s[4];
    #pragma unroll
    for (int ms = 0; ms < 4; ++ms) {
      s[ms] = (f32x4){0.f, 0.f, 0.f, 0.f};
      #pragma unroll
      for (int ks = 0; ks < 3; ++ks) {
        h16x8 kf = *(const h16x8*)&Ks[ms * 16 + l15][ks * 32 + lg * 8];
        s[ms] = __builtin_amdgcn_mfma_f32_16x16x32_f16(qf[ks], kf, s[ms], 0, 0, 0);
      }
    }

    // online softmax. lane holds S[n=(lg*4+r)][m = ms*16 + l15]
    float rm[4];
    #pragma unroll
    for (int r = 0; r < 4; ++r) {
      rm[r] = fmaxf(fmaxf(s[0][r], s[1][r]), fmaxf(s[2][r], s[3][r]));
      rm[r] = fmaxf(rm[r], __shfl_xor(rm[r], 1));
      rm[r] = fmaxf(rm[r], __shfl_xor(rm[r], 2));
      rm[r] = fmaxf(rm[r], __shfl_xor(rm[r], 4));
      rm[r] = fmaxf(rm[r], __shfl_xor(rm[r], 8));
    }
    float sc[4], rs[4];
    #pragma unroll
    for (int r = 0; r < 4; ++r) {
      float mn = fmaxf(m_run[r], rm[r]);
      sc[r] = __expf(m_run[r] - mn);
      m_run[r] = mn;
      float t0 = __expf(s[0][r] - mn); s[0][r] = t0;
      float t1 = __expf(s[1][r] - mn); s[1][r] = t1;
      float t2 = __expf(s[2][r] - mn); s[2][r] = t2;
      float t3 = __expf(s[3][r] - mn); s[3][r] = t3;
      rs[r] = (t0 + t1) + (t2 + t3);
      rs[r] += __shfl_xor(rs[r], 1);
      rs[r] += __shfl_xor(rs[r], 2);
      rs[r] += __shfl_xor(rs[r], 4);
      rs[r] += __shfl_xor(rs[r], 8);
      l_run[r] = l_run[r] * sc[r] + rs[r];
    }
    #pragma unroll
    for (int o = 0; o < 6; ++o) {
      #pragma unroll
      for (int r = 0; r < 4; ++r) acc[o][r] *= sc[r];
    }
    // P -> per-wave LDS (re-layout D-frag -> A-frag)
    #pragma unroll
    for (int ms = 0; ms < 4; ++ms) {
      #pragma unroll
      for (int r = 0; r < 4; ++r)
        Ps[wv][lg * 4 + r][ms * 16 + l15] = f2h(s[ms][r]);
    }
    asm volatile("s_waitcnt lgkmcnt(0)" ::: "memory");
    __builtin_amdgcn_sched_barrier(0);

    // PV: y[n][o] += P[n][m] * V[m][o]; A-frag row = l15, k = lg*8+j
    #pragma unroll
    for (int msl = 0; msl < 2; ++msl) {
      h16x8 pf = *(const h16x8*)&Ps[wv][l15][msl * 32 + lg * 8];
      #pragma unroll
      for (int o = 0; o < 6; ++o) {
        h16x8 vf = *(const h16x8*)&Vs[o * 16 + l15][msl * 32 + lg * 8];
        acc[o] = __builtin_amdgcn_mfma_f32_16x16x32_f16(pf, vf, acc[o], 0, 0, 0);
      }
    }
  }

  // epilogue: yT[b][n][o] = acc / l_run
  #pragma unroll
  for (int r = 0; r < 4; ++r) {
    float inv = 1.0f / l_run[r];
    int n = q0 + wv * 16 + lg * 4 + r;
    float* dst = yT + ((size_t)(b * NN + n)) * OO + l15;
    #pragma unroll
    for (int o = 0; o < 6; ++o) dst[o * 16] = acc[o][r] * inv;
  }
}

// ---------------- Kernel 3: W projection + residual ----------------
__global__ __launch_bounds__(256) void outproj_kernel(
    const float* __restrict__ x, const float* __restrict__ Ww,
    const float* __restrict__ Wb, const float* __restrict__ yT,
    float* __restrict__ out)
{
  __shared__ float ys[OO][66];   // transposed y tile: [o][n], padded
  const int b = blockIdx.y;
  const int n0 = blockIdx.x * 64;
  const int tid = threadIdx.x;
  #pragma unroll
  for (int it = 0; it < 6; ++it) {
    int idx = tid + it * 256;                 // 0..1535 : 64 rows x 24 float4
    int n = idx / 24, o4 = idx % 24;
    float4 v = *(const float4*)(yT + ((size_t)(b * NN + n0 + n)) * OO + o4 * 4);
    ys[o4 * 4 + 0][n] = v.x; ys[o4 * 4 + 1][n] = v.y;
    ys[o4 * 4 + 2][n] = v.z; ys[o4 * 4 + 3][n] = v.w;
  }
  __syncthreads();
  const int lane = tid & 63;
  const int cb = (tid >> 6) * 48;             // wave-uniform c-range
  float acc[48];
  #pragma unroll
  for (int i = 0; i < 48; ++i)
    acc[i] = x[((size_t)(b * CC + cb + i)) * NN + n0 + lane] + Wb[cb + i];
  for (int o = 0; o < OO; o += 2) {
    float y0 = ys[o][lane], y1 = ys[o + 1][lane];
    #pragma unroll
    for (int i = 0; i < 48; ++i)
      acc[i] += Ww[(cb + i) * OO + o] * y0 + Ww[(cb + i) * OO + o + 1] * y1;
  }
  #pragma unroll
  for (int i = 0; i < 48; ++i)
    out[((size_t)(b * CC + cb + i)) * NN + n0 + lane] = acc[i];
}

extern "C" void kernel_launch(void* const* d_in, const int* in_sizes, int n_in,
                              void* d_out, int out_size, void* d_ws, size_t ws_size,
                              hipStream_t stream) {
  const float* x    = (const float*)d_in[0];
  const float* g_w  = (const float*)d_in[1];
  const float* g_b  = (const float*)d_in[2];
  const float* th_w = (const float*)d_in[3];
  const float* th_b = (const float*)d_in[4];
  const float* ph_w = (const float*)d_in[5];
  const float* ph_b = (const float*)d_in[6];
  const float* W_w  = (const float*)d_in[7];
  const float* W_b  = (const float*)d_in[8];
  float* out = (float*)d_out;

  char* ws = (char*)d_ws;
  const size_t projB = (size_t)NB * NN * OO * sizeof(u16);   // 6.29 MB each
  u16* QT = (u16*)ws;
  u16* KT = (u16*)(ws + projB);
  u16* Vn = (u16*)(ws + 2 * projB);
  float* yT = (float*)(ws + 3 * projB);                      // 12.6 MB fp32

  dim3 grid(64, NB), blk(256);
  hipLaunchKernelGGL(proj_kernel, grid, blk, 0, stream,
                     x, g_w, g_b, th_w, th_b, ph_w, ph_b, QT, KT, Vn);
  hipLaunchKernelGGL(attn_kernel, grid, blk, 0, stream, QT, KT, Vn, yT);
  hipLaunchKernelGGL(outproj_kernel, grid, blk, 0, stream, x, W_w, W_b, yT, out);
}

// Round 3
// 237.836 us; speedup vs baseline: 2.4109x; 2.4109x over previous
//
#include <hip/hip_runtime.h>

typedef unsigned short u16;
typedef float f32x4 __attribute__((ext_vector_type(4)));
typedef _Float16 h16x8 __attribute__((ext_vector_type(8)));
typedef u16 u16x4 __attribute__((ext_vector_type(4)));

#define NB 8
#define CC 192
#define OO 96
#define NN 4096
#define XPAD 200   // row stride 400B -> bank starts 4n%32: 8 distinct, ~2-way (free)
#define YPAD 104   // row stride 208B -> bank starts 20r%32: 8 distinct, ~2-way

static __device__ __forceinline__ u16 f2h(float f) {
  _Float16 h = (_Float16)f;
  return __builtin_bit_cast(u16, h);
}

// ---------------- Kernel 1: theta/phi/g projections as fp16 MFMA GEMMs ----------------
// C_theta[n][o], C_phi[n][o] -> QT,KT [B,N,96]; C_g[o][n] -> Vn [B,96,N].
// One transposed x-tile Xs[n][c] serves as A (theta/phi) and B (g) operand.
__global__ __launch_bounds__(256) void proj_kernel(
    const float* __restrict__ x,
    const float* __restrict__ g_w, const float* __restrict__ g_b,
    const float* __restrict__ th_w, const float* __restrict__ th_b,
    const float* __restrict__ ph_w, const float* __restrict__ ph_b,
    u16* __restrict__ QT, u16* __restrict__ KT, u16* __restrict__ Vn)
{
  __shared__ __align__(16) u16 Xs[64][XPAD];   // 25.6 KB
  __shared__ __align__(16) u16 Ws[96][XPAD];   // 38.4 KB (one projection at a time)
  const int b = blockIdx.y, n0 = blockIdx.x * 64, tid = threadIdx.x;
  const int lane = tid & 63, wv = tid >> 6, l15 = lane & 15, lg = lane >> 4;

  // stage Xs transposed: x[b][c][n0+q*4+j] -> Xs[q*4+j][c]   (fp32 -> fp16)
  #pragma unroll
  for (int it = 0; it < 12; ++it) {
    int idx = tid + it * 256;                 // 0..3071
    int c = idx >> 4, q = idx & 15;
    float4 v = *(const float4*)(x + ((size_t)(b * CC + c)) * NN + n0 + q * 4);
    Xs[q * 4 + 0][c] = f2h(v.x); Xs[q * 4 + 1][c] = f2h(v.y);
    Xs[q * 4 + 2][c] = f2h(v.z); Xs[q * 4 + 3][c] = f2h(v.w);
  }

  for (int p = 0; p < 3; ++p) {
    const float* w    = (p == 0) ? th_w : (p == 1) ? ph_w : g_w;
    const float* bias = (p == 0) ? th_b : (p == 1) ? ph_b : g_b;
    __syncthreads();   // Xs ready (p=0) / previous phase's Ws readers done (p>0)
    // stage Ws: 96x192 fp32 -> fp16 : 4608 float4, 18 per thread
    #pragma unroll
    for (int it = 0; it < 18; ++it) {
      int idx = tid + it * 256;
      int r = idx / 48, q = idx % 48;
      float4 v = *(const float4*)(w + r * CC + q * 4);
      u16x4 h; h[0] = f2h(v.x); h[1] = f2h(v.y); h[2] = f2h(v.z); h[3] = f2h(v.w);
      *(u16x4*)&Ws[r][q * 4] = h;
    }
    __syncthreads();

    f32x4 acc[6];
    #pragma unroll
    for (int of = 0; of < 6; ++of) acc[of] = (f32x4){0.f, 0.f, 0.f, 0.f};
    #pragma unroll
    for (int ks = 0; ks < 6; ++ks) {
      h16x8 xa = *(const h16x8*)&Xs[wv * 16 + l15][ks * 32 + lg * 8];
      #pragma unroll
      for (int of = 0; of < 6; ++of) {
        h16x8 wf = *(const h16x8*)&Ws[of * 16 + l15][ks * 32 + lg * 8];
        if (p < 2) acc[of] = __builtin_amdgcn_mfma_f32_16x16x32_f16(xa, wf, acc[of], 0, 0, 0);
        else       acc[of] = __builtin_amdgcn_mfma_f32_16x16x32_f16(wf, xa, acc[of], 0, 0, 0);
      }
    }

    if (p < 2) {   // C[n][o]: row=n=lg*4+r, col=o=l15
      u16* dst = (p == 0) ? QT : KT;
      #pragma unroll
      for (int of = 0; of < 6; ++of) {
        int o = of * 16 + l15;
        float bo = bias[o];
        #pragma unroll
        for (int r = 0; r < 4; ++r) {
          int n = n0 + wv * 16 + lg * 4 + r;
          dst[((size_t)(b * NN + n)) * OO + o] = f2h(acc[of][r] + bo);
        }
      }
    } else {       // C[o][n]: row=o, col=n
      #pragma unroll
      for (int of = 0; of < 6; ++of) {
        #pragma unroll
        for (int r = 0; r < 4; ++r) {
          int o = of * 16 + lg * 4 + r;
          int n = n0 + wv * 16 + l15;
          Vn[((size_t)(b * OO + o)) * NN + n] = f2h(acc[of][r] + bias[o]);
        }
      }
    }
  }
}

// ---------------- Kernel 2: flash attention core (fp16 MFMA) ----------------
__global__ __launch_bounds__(256) void attn_kernel(
    const u16* __restrict__ QT, const u16* __restrict__ KT,
    const u16* __restrict__ Vn, u16* __restrict__ yT16)
{
  __shared__ __align__(16) u16 Ks[64][104];     // 96 + 8 pad
  __shared__ __align__(16) u16 Vs[OO][72];      // 64 + 8 pad
  __shared__ __align__(16) u16 Ps[4][16][72];   // per-wave P tile
  const int b = blockIdx.y;
  const int q0 = blockIdx.x * 64;
  const int tid = threadIdx.x;
  const int lane = tid & 63;
  const int wv = tid >> 6;
  const int l15 = lane & 15;
  const int lg = lane >> 4;

  const int qrow = q0 + wv * 16 + l15;
  h16x8 qf[3];
  #pragma unroll
  for (int ks = 0; ks < 3; ++ks)
    qf[ks] = *(const h16x8*)(QT + ((size_t)(b * NN + qrow)) * OO + ks * 32 + lg * 8);

  float m_run[4], l_run[4];
  f32x4 acc[6];
  #pragma unroll
  for (int r = 0; r < 4; ++r) { m_run[r] = -__builtin_inff(); l_run[r] = 0.f; }
  #pragma unroll
  for (int o = 0; o < 6; ++o) acc[o] = (f32x4){0.f, 0.f, 0.f, 0.f};

  for (int mt = 0; mt < 64; ++mt) {
    const int m0 = mt * 64;
    __syncthreads();
    #pragma unroll
    for (int it = 0; it < 3; ++it) {
      int idx = tid + it * 256;
      int r = idx / 12, c8 = idx % 12;
      float4 v = *(const float4*)(KT + ((size_t)(b * NN + m0 + r)) * OO + c8 * 8);
      *(float4*)&Ks[r][c8 * 8] = v;
    }
    #pragma unroll
    for (int it = 0; it < 3; ++it) {
      int idx = tid + it * 256;
      int o = idx >> 3, c8 = idx & 7;
      float4 v = *(const float4*)(Vn + ((size_t)(b * OO + o)) * NN + m0 + c8 * 8);
      *(float4*)&Vs[o][c8 * 8] = v;
    }
    __syncthreads();

    f32x4 s[4];
    #pragma unroll
    for (int ms = 0; ms < 4; ++ms) {
      s[ms] = (f32x4){0.f, 0.f, 0.f, 0.f};
      #pragma unroll
      for (int ks = 0; ks < 3; ++ks) {
        h16x8 kf = *(const h16x8*)&Ks[ms * 16 + l15][ks * 32 + lg * 8];
        s[ms] = __builtin_amdgcn_mfma_f32_16x16x32_f16(qf[ks], kf, s[ms], 0, 0, 0);
      }
    }

    float rm[4];
    #pragma unroll
    for (int r = 0; r < 4; ++r) {
      rm[r] = fmaxf(fmaxf(s[0][r], s[1][r]), fmaxf(s[2][r], s[3][r]));
      rm[r] = fmaxf(rm[r], __shfl_xor(rm[r], 1));
      rm[r] = fmaxf(rm[r], __shfl_xor(rm[r], 2));
      rm[r] = fmaxf(rm[r], __shfl_xor(rm[r], 4));
      rm[r] = fmaxf(rm[r], __shfl_xor(rm[r], 8));
    }
    float sc[4], rs[4];
    #pragma unroll
    for (int r = 0; r < 4; ++r) {
      float mn = fmaxf(m_run[r], rm[r]);
      sc[r] = __expf(m_run[r] - mn);
      m_run[r] = mn;
      float t0 = __expf(s[0][r] - mn); s[0][r] = t0;
      float t1 = __expf(s[1][r] - mn); s[1][r] = t1;
      float t2 = __expf(s[2][r] - mn); s[2][r] = t2;
      float t3 = __expf(s[3][r] - mn); s[3][r] = t3;
      rs[r] = (t0 + t1) + (t2 + t3);
      rs[r] += __shfl_xor(rs[r], 1);
      rs[r] += __shfl_xor(rs[r], 2);
      rs[r] += __shfl_xor(rs[r], 4);
      rs[r] += __shfl_xor(rs[r], 8);
      l_run[r] = l_run[r] * sc[r] + rs[r];
    }
    #pragma unroll
    for (int o = 0; o < 6; ++o) {
      #pragma unroll
      for (int r = 0; r < 4; ++r) acc[o][r] *= sc[r];
    }
    #pragma unroll
    for (int ms = 0; ms < 4; ++ms) {
      #pragma unroll
      for (int r = 0; r < 4; ++r)
        Ps[wv][lg * 4 + r][ms * 16 + l15] = f2h(s[ms][r]);
    }
    asm volatile("s_waitcnt lgkmcnt(0)" ::: "memory");
    __builtin_amdgcn_sched_barrier(0);

    #pragma unroll
    for (int msl = 0; msl < 2; ++msl) {
      h16x8 pf = *(const h16x8*)&Ps[wv][l15][msl * 32 + lg * 8];
      #pragma unroll
      for (int o = 0; o < 6; ++o) {
        h16x8 vf = *(const h16x8*)&Vs[o * 16 + l15][msl * 32 + lg * 8];
        acc[o] = __builtin_amdgcn_mfma_f32_16x16x32_f16(pf, vf, acc[o], 0, 0, 0);
      }
    }
  }

  // epilogue: yT16[b][n][o] = fp16(acc / l_run)
  #pragma unroll
  for (int r = 0; r < 4; ++r) {
    float inv = 1.0f / l_run[r];
    int n = q0 + wv * 16 + lg * 4 + r;
    u16* dst = yT16 + ((size_t)(b * NN + n)) * OO + l15;
    #pragma unroll
    for (int o = 0; o < 6; ++o) dst[o * 16] = f2h(acc[o][r] * inv);
  }
}

// ---------------- Kernel 3: W projection + residual as fp16 MFMA GEMM ----------------
// out[c][n] = x[c][n] + Wb[c] + sum_o Ww[c][o] * y[o][n]
__global__ __launch_bounds__(256) void outproj_kernel(
    const float* __restrict__ x, const float* __restrict__ Ww,
    const float* __restrict__ Wb, const u16* __restrict__ yT16,
    float* __restrict__ out)
{
  __shared__ __align__(16) u16 Wws[CC][YPAD];  // 39.9 KB
  __shared__ __align__(16) u16 Ys[64][YPAD];   // 13.3 KB
  const int b = blockIdx.y, n0 = blockIdx.x * 64, tid = threadIdx.x;
  const int lane = tid & 63, wv = tid >> 6, l15 = lane & 15, lg = lane >> 4;

  // stage Wws: 192x96 fp32 -> fp16
  #pragma unroll
  for (int it = 0; it < 18; ++it) {
    int idx = tid + it * 256;
    int r = idx / 24, q = idx % 24;
    float4 v = *(const float4*)(Ww + r * OO + q * 4);
    u16x4 h; h[0] = f2h(v.x); h[1] = f2h(v.y); h[2] = f2h(v.z); h[3] = f2h(v.w);
    *(u16x4*)&Wws[r][q * 4] = h;
  }
  // stage Ys: [64 n][96 o] fp16 from yT16
  #pragma unroll
  for (int it = 0; it < 3; ++it) {
    int idx = tid + it * 256;
    int n = idx / 12, q = idx % 12;
    *(float4*)&Ys[n][q * 8] =
        *(const float4*)(yT16 + ((size_t)(b * NN + n0 + n)) * OO + q * 8);
  }
  __syncthreads();

  f32x4 acc[12];
  #pragma unroll
  for (int cf = 0; cf < 12; ++cf) acc[cf] = (f32x4){0.f, 0.f, 0.f, 0.f};
  #pragma unroll
  for (int ks = 0; ks < 3; ++ks) {
    h16x8 yb = *(const h16x8*)&Ys[wv * 16 + l15][ks * 32 + lg * 8];
    #pragma unroll
    for (int cf = 0; cf < 12; ++cf) {
      h16x8 wa = *(const h16x8*)&Wws[cf * 16 + l15][ks * 32 + lg * 8];
      acc[cf] = __builtin_amdgcn_mfma_f32_16x16x32_f16(wa, yb, acc[cf], 0, 0, 0);
    }
  }
  // C[c][n]: row=c=cf*16+lg*4+r, col=n=l15. Fuse residual + bias.
  #pragma unroll
  for (int cf = 0; cf < 12; ++cf) {
    #pragma unroll
    for (int r = 0; r < 4; ++r) {
      int c = cf * 16 + lg * 4 + r;
      size_t off = ((size_t)(b * CC + c)) * NN + n0 + wv * 16 + l15;
      out[off] = acc[cf][r] + x[off] + Wb[c];
    }
  }
}

extern "C" void kernel_launch(void* const* d_in, const int* in_sizes, int n_in,
                              void* d_out, int out_size, void* d_ws, size_t ws_size,
                              hipStream_t stream) {
  const float* x    = (const float*)d_in[0];
  const float* g_w  = (const float*)d_in[1];
  const float* g_b  = (const float*)d_in[2];
  const float* th_w = (const float*)d_in[3];
  const float* th_b = (const float*)d_in[4];
  const float* ph_w = (const float*)d_in[5];
  const float* ph_b = (const float*)d_in[6];
  const float* W_w  = (const float*)d_in[7];
  const float* W_b  = (const float*)d_in[8];
  float* out = (float*)d_out;

  char* ws = (char*)d_ws;
  const size_t projB = (size_t)NB * NN * OO * sizeof(u16);   // 6.29 MB each
  u16* QT   = (u16*)ws;
  u16* KT   = (u16*)(ws + projB);
  u16* Vn   = (u16*)(ws + 2 * projB);
  u16* yT16 = (u16*)(ws + 3 * projB);

  dim3 grid(64, NB), blk(256);
  hipLaunchKernelGGL(proj_kernel, grid, blk, 0, stream,
                     x, g_w, g_b, th_w, th_b, ph_w, ph_b, QT, KT, Vn);
  hipLaunchKernelGGL(attn_kernel, grid, blk, 0, stream, QT, KT, Vn, yT16);
  hipLaunchKernelGGL(outproj_kernel, grid, blk, 0, stream, x, W_w, W_b, yT16, out);
}

// Round 6
// 106.740 us; speedup vs baseline: 5.3719x; 2.2282x over previous
//
#include <hip/hip_runtime.h>

typedef unsigned short u16;
typedef unsigned int u32;
typedef float f32x4 __attribute__((ext_vector_type(4)));
typedef float f32x16 __attribute__((ext_vector_type(16)));
typedef _Float16 h16x8 __attribute__((ext_vector_type(8)));
typedef u32 u32x4 __attribute__((ext_vector_type(4)));
typedef u32 u32x2 __attribute__((ext_vector_type(2)));
typedef u16 u16x4 __attribute__((ext_vector_type(4)));

#define NB 8
#define CC 192
#define OO 96
#define NN 4096
#define NSPLIT 3
#define XPAD 200   // proj LDS row pad

static __device__ __forceinline__ u16 f2h(float f) {
  _Float16 h = (_Float16)f;
  return __builtin_bit_cast(u16, h);
}
static __device__ __forceinline__ float h2f(u16 u) {
  return (float)__builtin_bit_cast(_Float16, u);
}
static __device__ __forceinline__ void gl_lds16(const u16* g, u16* l) {
  __builtin_amdgcn_global_load_lds(
      (const __attribute__((address_space(1))) void*)g,
      (__attribute__((address_space(3))) void*)l, 16, 0, 0);
}
// ret0 = [a.lanes0-31 | b.lanes0-31], ret1 = [a.lanes32-63 | b.lanes32-63]
static __device__ __forceinline__ void plane_swap(u32& a, u32& b) {
  u32x2 r = __builtin_amdgcn_permlane32_swap(a, b, false, false);
  a = r[0]; b = r[1];
}
// combine value with the cross-half partner (same l31) via op
static __device__ __forceinline__ float half_combine_max(float x) {
  u32 a = __builtin_bit_cast(u32, x), b = a;
  plane_swap(a, b);
  return fmaxf(__builtin_bit_cast(float, a), __builtin_bit_cast(float, b));
}
static __device__ __forceinline__ float half_combine_sum(float x) {
  u32 a = __builtin_bit_cast(u32, x), b = a;
  plane_swap(a, b);
  return __builtin_bit_cast(float, a) + __builtin_bit_cast(float, b);
}

// ---------------- Kernel 1: theta/phi/g projections as fp16 MFMA GEMMs ----------------
// Outputs in MFMA-fragment-preswizzled layouts (32x32x16 frags):
//  QB[b][nc]: B-frag, elem (o,n): off = ((o>>3)*32 + (n&31))*8 + (o&7)
//  KA[b][mc]: A-frag, same formula with m
//  VA[b][m>>4]: A-frag of V^T: off = (((o>>5)*2 + ((m>>3)&1))*32 + (o&31))*8 + (m&7)
__global__ __launch_bounds__(256) void proj_kernel(
    const float* __restrict__ x,
    const float* __restrict__ g_w, const float* __restrict__ g_b,
    const float* __restrict__ th_w, const float* __restrict__ th_b,
    const float* __restrict__ ph_w, const float* __restrict__ ph_b,
    u16* __restrict__ QB, u16* __restrict__ KA, u16* __restrict__ VA)
{
  __shared__ __align__(16) u16 Xs[64][XPAD];
  __shared__ __align__(16) u16 Ws[96][XPAD];
  const int b = blockIdx.y, n0 = blockIdx.x * 64, tid = threadIdx.x;
  const int lane = tid & 63, wv = tid >> 6, l15 = lane & 15, lg = lane >> 4;

  #pragma unroll
  for (int it = 0; it < 12; ++it) {
    int idx = tid + it * 256;
    int c = idx >> 4, q = idx & 15;
    float4 v = *(const float4*)(x + ((size_t)(b * CC + c)) * NN + n0 + q * 4);
    Xs[q * 4 + 0][c] = f2h(v.x); Xs[q * 4 + 1][c] = f2h(v.y);
    Xs[q * 4 + 2][c] = f2h(v.z); Xs[q * 4 + 3][c] = f2h(v.w);
  }

  for (int p = 0; p < 3; ++p) {
    const float* w    = (p == 0) ? th_w : (p == 1) ? ph_w : g_w;
    const float* bias = (p == 0) ? th_b : (p == 1) ? ph_b : g_b;
    __syncthreads();
    #pragma unroll
    for (int it = 0; it < 18; ++it) {
      int idx = tid + it * 256;
      int r = idx / 48, q = idx % 48;
      float4 v = *(const float4*)(w + r * CC + q * 4);
      u16x4 hh; hh[0] = f2h(v.x); hh[1] = f2h(v.y); hh[2] = f2h(v.z); hh[3] = f2h(v.w);
      *(u16x4*)&Ws[r][q * 4] = hh;
    }
    __syncthreads();

    f32x4 acc[6];
    #pragma unroll
    for (int of = 0; of < 6; ++of) acc[of] = (f32x4){0.f, 0.f, 0.f, 0.f};
    #pragma unroll
    for (int ks = 0; ks < 6; ++ks) {
      h16x8 xa = *(const h16x8*)&Xs[wv * 16 + l15][ks * 32 + lg * 8];
      #pragma unroll
      for (int of = 0; of < 6; ++of) {
        h16x8 wf = *(const h16x8*)&Ws[of * 16 + l15][ks * 32 + lg * 8];
        if (p < 2) acc[of] = __builtin_amdgcn_mfma_f32_16x16x32_f16(xa, wf, acc[of], 0, 0, 0);
        else       acc[of] = __builtin_amdgcn_mfma_f32_16x16x32_f16(wf, xa, acc[of], 0, 0, 0);
      }
    }

    if (p < 2) {   // C[n][o]: n = n0+wv*16+lg*4+r, o = of*16+l15  ->  QB / KA
      u16* dst = (p == 0) ? QB : KA;
      #pragma unroll
      for (int of = 0; of < 6; ++of) {
        int o = of * 16 + l15;
        float bo = bias[o];
        int kch = of * 2 + (l15 >> 3);
        #pragma unroll
        for (int r = 0; r < 4; ++r) {
          int n = n0 + wv * 16 + lg * 4 + r;
          int idx = (b * 128 + (n >> 5)) * 3072 + (kch * 32 + (n & 31)) * 8 + (o & 7);
          dst[idx] = f2h(acc[of][r] + bo);
        }
      }
    } else {       // C[o][m]: o = of*16+lg*4+r, m = n0+wv*16+l15  ->  VA
      #pragma unroll
      for (int of = 0; of < 6; ++of) {
        #pragma unroll
        for (int r = 0; r < 4; ++r) {
          int o = of * 16 + lg * 4 + r;
          int m = n0 + wv * 16 + l15;
          int idx = (b * 256 + (m >> 4)) * 1536 +
                    (((o >> 5) * 2 + ((m >> 3) & 1)) * 32 + (o & 31)) * 8 + (m & 7);
          VA[idx] = f2h(acc[of][r] + bias[o]);
        }
      }
    }
  }
}

// ---------------- Kernel 2: flash attention core (32x32 swapped-QK, in-reg softmax) ----
// Block: 4 waves x 32 q-rows = 128 q. KV split over NSPLIT z-blocks, 64-m tiles,
// double-buffered LDS via global_load_lds + counted vmcnt.
__global__ __launch_bounds__(256, 3) void attn_kernel(
    const u16* __restrict__ QB, const u16* __restrict__ KA,
    const u16* __restrict__ VA, u16* __restrict__ yP, float* __restrict__ ml)
{
  __shared__ __align__(16) u16 Ks[2][6144];
  __shared__ __align__(16) u16 Vs[2][6144];
  const int b   = blockIdx.x;           // XCD-swizzle: id%8 == batch
  const int qt  = blockIdx.y;
  const int sp  = blockIdx.z;
  const int tid = threadIdx.x;
  const int lane = tid & 63;
  const int wv  = tid >> 6;
  const int l31 = lane & 31;
  const int h   = lane >> 5;

  const int t_start = (64 * sp) / NSPLIT;
  const int t_end   = (64 * (sp + 1)) / NSPLIT;
  const int nt = t_end - t_start;

  const int nc = qt * 4 + wv;
  const u16* qb = QB + (size_t)(b * 128 + nc) * 3072;
  h16x8 qf[6];
  #pragma unroll
  for (int ks = 0; ks < 6; ++ks)
    qf[ks] = *(const h16x8*)(qb + ((ks * 2 + h) * 32 + l31) * 8);

  const u16* KAb = KA + (size_t)b * (128 * 3072);
  const u16* VAb = VA + (size_t)b * (256 * 1536);

  f32x16 acc[3];
  #pragma unroll
  for (int ob = 0; ob < 3; ++ob)
    #pragma unroll
    for (int i = 0; i < 16; ++i) acc[ob][i] = 0.f;
  float m_run = -__builtin_inff(), l_run = 0.f;

  // prologue stage: tile = 6144 u16 = 12288 B; 256 thr x 16 B x 3 iters
  {
    const u16* gk = KAb + (size_t)t_start * 6144;
    const u16* gv = VAb + (size_t)t_start * 6144;
    #pragma unroll
    for (int i = 0; i < 3; ++i) gl_lds16(gk + tid * 8 + i * 2048, &Ks[0][tid * 8 + i * 2048]);
    #pragma unroll
    for (int i = 0; i < 3; ++i) gl_lds16(gv + tid * 8 + i * 2048, &Vs[0][tid * 8 + i * 2048]);
  }

  for (int t = 0; t < nt; ++t) {
    const int bf = t & 1;
    if (t + 1 < nt) {
      const u16* gk = KAb + (size_t)(t_start + t + 1) * 6144;
      const u16* gv = VAb + (size_t)(t_start + t + 1) * 6144;
      #pragma unroll
      for (int i = 0; i < 3; ++i) gl_lds16(gk + tid * 8 + i * 2048, &Ks[bf ^ 1][tid * 8 + i * 2048]);
      #pragma unroll
      for (int i = 0; i < 3; ++i) gl_lds16(gv + tid * 8 + i * 2048, &Vs[bf ^ 1][tid * 8 + i * 2048]);
      asm volatile("s_waitcnt vmcnt(6)" ::: "memory");   // drain current tile, keep 6 in flight
    } else {
      asm volatile("s_waitcnt vmcnt(0)" ::: "memory");
    }
    __builtin_amdgcn_s_barrier();
    __builtin_amdgcn_sched_barrier(0);

    #pragma unroll
    for (int c = 0; c < 2; ++c) {
      // QK^T (swapped): S^T[m][n], lane holds col n=l31
      f32x16 S;
      #pragma unroll
      for (int i = 0; i < 16; ++i) S[i] = 0.f;
      const u16* kbase = &Ks[bf][c * 3072];
      #pragma unroll
      for (int ks = 0; ks < 6; ++ks) {
        h16x8 kf = *(const h16x8*)(kbase + ((ks * 2 + h) * 32 + l31) * 8);
        S = __builtin_amdgcn_mfma_f32_32x32x16_f16(kf, qf[ks], S, 0, 0, 0);
      }
      // chunk max: in-reg tree (16 regs) + cross-half combine
      float v[16];
      #pragma unroll
      for (int i = 0; i < 16; ++i) v[i] = S[i];
      #pragma unroll
      for (int st = 8; st >= 1; st >>= 1)
        #pragma unroll
        for (int i = 0; i < 8; ++i) if (i < st) v[i] = fmaxf(v[i], v[i + st]);
      float pmax = half_combine_max(v[0]);
      // defer-max rescale (THR=8)
      if (__ballot(pmax > m_run + 8.0f)) {
        float mn = fmaxf(m_run, pmax);
        float sc = __expf(m_run - mn);
        m_run = mn; l_run *= sc;
        #pragma unroll
        for (int ob = 0; ob < 3; ++ob)
          #pragma unroll
          for (int i = 0; i < 16; ++i) acc[ob][i] *= sc;
      }
      // P = exp(S - m_run), row sum
      float p[16];
      #pragma unroll
      for (int i = 0; i < 16; ++i) p[i] = __expf(S[i] - m_run);
      #pragma unroll
      for (int i = 0; i < 16; ++i) v[i] = p[i];
      #pragma unroll
      for (int st = 8; st >= 1; st >>= 1)
        #pragma unroll
        for (int i = 0; i < 8; ++i) if (i < st) v[i] += v[i + st];
      l_run += half_combine_sum(v[0]);
      // P^T -> B-frags: cvt_pk pairs then half-swaps
      u32 pk[8];
      #pragma unroll
      for (int i = 0; i < 8; ++i)
        pk[i] = __builtin_bit_cast(u32, __builtin_amdgcn_cvt_pkrtz(p[2 * i], p[2 * i + 1]));
      plane_swap(pk[0], pk[2]); plane_swap(pk[1], pk[3]);
      plane_swap(pk[4], pk[6]); plane_swap(pk[5], pk[7]);
      u32x4 bw0 = {pk[0], pk[1], pk[2], pk[3]};
      u32x4 bw1 = {pk[4], pk[5], pk[6], pk[7]};
      h16x8 pf0 = __builtin_bit_cast(h16x8, bw0);
      h16x8 pf1 = __builtin_bit_cast(h16x8, bw1);
      // PV: y^T[o][n] += V^T[o][m] * P^T[m][n]
      const u16* vbase = &Vs[bf][c * 3072];
      #pragma unroll
      for (int s2 = 0; s2 < 2; ++s2) {
        h16x8 pfr = s2 ? pf1 : pf0;
        #pragma unroll
        for (int ob = 0; ob < 3; ++ob) {
          h16x8 vf = *(const h16x8*)(vbase + (((s2 * 3 + ob) * 2 + h) * 32 + l31) * 8);
          acc[ob] = __builtin_amdgcn_mfma_f32_32x32x16_f16(vf, pfr, acc[ob], 0, 0, 0);
        }
      }
    }
    __builtin_amdgcn_s_barrier();
    __builtin_amdgcn_sched_barrier(0);
  }

  // epilogue: normalized partial y_s = acc/l_run (f16) + (m,l) per row
  float inv = 1.0f / l_run;
  int nglob = nc * 32 + l31;
  u16* yp = yP + (((size_t)sp * NB + b) * NN + nglob) * OO;
  #pragma unroll
  for (int ob = 0; ob < 3; ++ob) {
    #pragma unroll
    for (int rq = 0; rq < 4; ++rq) {
      int o0 = ob * 32 + rq * 8 + h * 4;
      u32 w0 = __builtin_bit_cast(u32,
          __builtin_amdgcn_cvt_pkrtz(acc[ob][rq * 4 + 0] * inv, acc[ob][rq * 4 + 1] * inv));
      u32 w1 = __builtin_bit_cast(u32,
          __builtin_amdgcn_cvt_pkrtz(acc[ob][rq * 4 + 2] * inv, acc[ob][rq * 4 + 3] * inv));
      uint2 pr; pr.x = w0; pr.y = w1;
      *(uint2*)&yp[o0] = pr;
    }
  }
  if (h == 0) {
    float2 v2; v2.x = m_run; v2.y = l_run;
    *(float2*)&ml[(((size_t)sp * NB + b) * NN + nglob) * 2] = v2;
  }
}

// ---------------- Kernel 2b: merge KV-split partials ----------------
__global__ __launch_bounds__(256) void merge_kernel(
    const u16* __restrict__ yP, const float* __restrict__ ml, u16* __restrict__ yT16)
{
  size_t t = (size_t)blockIdx.x * 256 + threadIdx.x;
  int o = (int)(t % OO);
  size_t bn = t / OO;
  const size_t SB = (size_t)NB * NN;
  float m0 = ml[(0 * SB + bn) * 2], l0 = ml[(0 * SB + bn) * 2 + 1];
  float m1 = ml[(1 * SB + bn) * 2], l1 = ml[(1 * SB + bn) * 2 + 1];
  float m2 = ml[(2 * SB + bn) * 2], l2 = ml[(2 * SB + bn) * 2 + 1];
  float M = fmaxf(m0, fmaxf(m1, m2));
  float w0 = l0 * __expf(m0 - M), w1 = l1 * __expf(m1 - M), w2 = l2 * __expf(m2 - M);
  float y0 = h2f(yP[(0 * SB + bn) * OO + o]);
  float y1 = h2f(yP[(1 * SB + bn) * OO + o]);
  float y2 = h2f(yP[(2 * SB + bn) * OO + o]);
  float y = (w0 * y0 + w1 * y1 + w2 * y2) / (w0 + w1 + w2);
  yT16[bn * OO + o] = f2h(y);
}

// ---------------- Kernel 3: W projection + residual as fp16 MFMA GEMM ----------------
#define YPAD 104
__global__ __launch_bounds__(256) void outproj_kernel(
    const float* __restrict__ x, const float* __restrict__ Ww,
    const float* __restrict__ Wb, const u16* __restrict__ yT16,
    float* __restrict__ out)
{
  __shared__ __align__(16) u16 Wws[CC][YPAD];
  __shared__ __align__(16) u16 Ys[64][YPAD];
  const int b = blockIdx.y, n0 = blockIdx.x * 64, tid = threadIdx.x;
  const int lane = tid & 63, wv = tid >> 6, l15 = lane & 15, lg = lane >> 4;

  #pragma unroll
  for (int it = 0; it < 18; ++it) {
    int idx = tid + it * 256;
    int r = idx / 24, q = idx % 24;
    float4 v = *(const float4*)(Ww + r * OO + q * 4);
    u16x4 hh; hh[0] = f2h(v.x); hh[1] = f2h(v.y); hh[2] = f2h(v.z); hh[3] = f2h(v.w);
    *(u16x4*)&Wws[r][q * 4] = hh;
  }
  #pragma unroll
  for (int it = 0; it < 3; ++it) {
    int idx = tid + it * 256;
    int n = idx / 12, q = idx % 12;
    *(float4*)&Ys[n][q * 8] =
        *(const float4*)(yT16 + ((size_t)(b * NN + n0 + n)) * OO + q * 8);
  }
  __syncthreads();

  f32x4 acc[12];
  #pragma unroll
  for (int cf = 0; cf < 12; ++cf) acc[cf] = (f32x4){0.f, 0.f, 0.f, 0.f};
  #pragma unroll
  for (int ks = 0; ks < 3; ++ks) {
    h16x8 yb = *(const h16x8*)&Ys[wv * 16 + l15][ks * 32 + lg * 8];
    #pragma unroll
    for (int cf = 0; cf < 12; ++cf) {
      h16x8 wa = *(const h16x8*)&Wws[cf * 16 + l15][ks * 32 + lg * 8];
      acc[cf] = __builtin_amdgcn_mfma_f32_16x16x32_f16(wa, yb, acc[cf], 0, 0, 0);
    }
  }
  #pragma unroll
  for (int cf = 0; cf < 12; ++cf) {
    #pragma unroll
    for (int r = 0; r < 4; ++r) {
      int c = cf * 16 + lg * 4 + r;
      size_t off = ((size_t)(b * CC + c)) * NN + n0 + wv * 16 + l15;
      out[off] = acc[cf][r] + x[off] + Wb[c];
    }
  }
}

extern "C" void kernel_launch(void* const* d_in, const int* in_sizes, int n_in,
                              void* d_out, int out_size, void* d_ws, size_t ws_size,
                              hipStream_t stream) {
  const float* x    = (const float*)d_in[0];
  const float* g_w  = (const float*)d_in[1];
  const float* g_b  = (const float*)d_in[2];
  const float* th_w = (const float*)d_in[3];
  const float* th_b = (const float*)d_in[4];
  const float* ph_w = (const float*)d_in[5];
  const float* ph_b = (const float*)d_in[6];
  const float* W_w  = (const float*)d_in[7];
  const float* W_b  = (const float*)d_in[8];
  float* out = (float*)d_out;

  char* ws = (char*)d_ws;
  const size_t projB = (size_t)NB * NN * OO * sizeof(u16);   // 6.29 MB
  u16* QB   = (u16*)ws;
  u16* KA   = (u16*)(ws + projB);
  u16* VA   = (u16*)(ws + 2 * projB);
  u16* yP   = (u16*)(ws + 3 * projB);                        // 3 * projB
  float* ml = (float*)(ws + 6 * projB);                      // 786 KB
  u16* yT16 = QB;   // QB is dead after attn; merge overwrites it

  dim3 blk(256);
  dim3 gproj(64, NB);
  hipLaunchKernelGGL(proj_kernel, gproj, blk, 0, stream,
                     x, g_w, g_b, th_w, th_b, ph_w, ph_b, QB, KA, VA);
  dim3 gattn(NB, 32, NSPLIT);
  hipLaunchKernelGGL(attn_kernel, gattn, blk, 0, stream, QB, KA, VA, yP, ml);
  dim3 gmerge((NB * NN * OO) / 256);
  hipLaunchKernelGGL(merge_kernel, gmerge, blk, 0, stream, yP, ml, yT16);
  dim3 gout(64, NB);
  hipLaunchKernelGGL(outproj_kernel, gout, blk, 0, stream, x, W_w, W_b, yT16, out);
}